// Round 7
// baseline (384.605 us; speedup 1.0000x reference)
//
#include <hip/hip_runtime.h>

// MHA forward: x(2,2048,2048) fp32, Wq/Wk/Wv/Wo (2048,2048) fp32 -> out fp32.
// R10: attn load balance restored. R9's grid-512 heavy-first gave per-CU work
//      sums of 20..48 iter-volumes (measured occupancy 26% == the imbalance
//      math) -> makespan set by 48-iter CUs. Now each block internally pairs
//      q-tiles (pr, 15-pr): exactly 36 iterations per block, uniform by
//      construction, immune to dispatch order. Grid 256 = 1 block/CU.
//      Inner loop (P cvt_pk pack, sigma-V, diagonal skips) = R9 verbatim.
//      GEMMs (R8 BN=192 ring-2) and cvt unchanged.

#define SEQ 2048
#define DMODEL 2048
#define NH 16
#define HD 128

typedef __attribute__((ext_vector_type(8))) short bf16x8;  // 8 bf16 = 4 VGPRs
typedef __attribute__((ext_vector_type(4))) float f32x4;

__device__ __forceinline__ unsigned short f2bf(float f) {  // RNE fp32->bf16
  unsigned int u = __float_as_uint(f);
  u += 0x7fffu + ((u >> 16) & 1u);
  return (unsigned short)(u >> 16);
}

__device__ __forceinline__ void g2l16(const void* g, void* l) {
  __builtin_amdgcn_global_load_lds((const __attribute__((address_space(1))) void*)g,
                                   (__attribute__((address_space(3))) void*)l,
                                   16, 0, 0);
}

__device__ __forceinline__ f32x4 mfma16(bf16x8 a, bf16x8 b, f32x4 c) {
  return __builtin_amdgcn_mfma_f32_16x16x32_bf16(a, b, c, 0, 0, 0);
}

template <int CTRL>
__device__ __forceinline__ float dpp_ror(float v) {
  return __int_as_float(__builtin_amdgcn_mov_dpp(__float_as_int(v), CTRL, 0xf, 0xf, false));
}
__device__ __forceinline__ float red_max16(float v) {
  v = fmaxf(v, dpp_ror<0x128>(v));
  v = fmaxf(v, dpp_ror<0x124>(v));
  v = fmaxf(v, dpp_ror<0x122>(v));
  v = fmaxf(v, dpp_ror<0x121>(v));
  return v;
}
__device__ __forceinline__ float red_sum16(float v) {
  v += dpp_ror<0x128>(v);
  v += dpp_ror<0x124>(v);
  v += dpp_ror<0x122>(v);
  v += dpp_ror<0x121>(v);
  return v;
}

// one launch: converts x + all four weights to bf16, permutes Wq/Wk rows
// within-head (RoPE pairs -> adjacent 16-col fragments), fills rope table.
__global__ __launch_bounds__(256) void cvt_all(const float* __restrict__ x,
                                               const float* __restrict__ wq,
                                               const float* __restrict__ wk,
                                               const float* __restrict__ wv,
                                               const float* __restrict__ wo,
                                               unsigned short* __restrict__ dst0,
                                               float2* __restrict__ rtab) {
  const int b = blockIdx.x;
  if (b >= 24576) {  // rope cos/sin table: 2048 x 64
    const int idx = (b - 24576) * 256 + threadIdx.x;  // [0, 131072)
    const int s = idx >> 6, d = idx & 63;
    float sn, cs;
    sincosf((float)s * exp2f(-0.20762050593046f * (float)d), &sn, &cs);
    rtab[idx] = make_float2(cs, sn);
    return;
  }
  const float* src;
  unsigned short* dst;
  int idx, r = -1;
  if (b < 8192) {  // x: 2097152 float4's
    src = x; dst = dst0; idx = b * 256 + threadIdx.x;
  } else {
    r = (b - 8192) >> 12;  // 4096 blocks per weight
    src = (r == 0) ? wq : (r == 1) ? wk : (r == 2) ? wv : wo;
    dst = dst0 + (size_t)2 * SEQ * DMODEL + (size_t)r * DMODEL * DMODEL;
    idx = ((b - 8192) & 4095) * 256 + threadIdx.x;
  }
  const float4 v = ((const float4*)src)[idx];
  ushort4 o;
  o.x = f2bf(v.x); o.y = f2bf(v.y); o.z = f2bf(v.z); o.w = f2bf(v.w);
  int widx = idx;
  if (r == 0 || r == 1) {  // permute Wq/Wk output-feature rows within head
    const int row = idx >> 9, col = idx & 511;
    const int o_ = row & 127;
    const int e = (((o_ >> 4) & 3) << 5) | (((o_ >> 6) & 1) << 4) | (o_ & 15);
    widx = (((row & ~127) | e) << 9) | col;
  }
  ((ushort4*)dst)[widx] = o;
}

// ---------------------------------------------------------------------------
// Pipelined GEMM core: C[m,n] = sum_k A[m,k]*B[n,k].
// BM=256, BN=192(MODE0)/128(MODE1), BK=64. 512 threads = 8 waves (4M x 2N).
// Ring-2 LDS; stage t+1 interleaved with compute of t; vmcnt(0)+barrier per
// tile. Natural dim3 grid (gridDim.x%8==0 -> B panels XCD-L2-resident).
// MODE 0: fused QKV; V keys are stored sigma-permuted within 64-blocks so the
// attention kernel's packed-P PV MFMA sees a consistent k-order.
// ---------------------------------------------------------------------------
template <int MODE>
__global__ __launch_bounds__(512, 2) void gemm_pipe(
    const unsigned short* __restrict__ A,
    const unsigned short* __restrict__ B,
    unsigned short* __restrict__ obf,   // MODE0: qb (kb=+NX, vb=+2NX)
    float* __restrict__ of32,           // MODE1: output
    const float2* __restrict__ rtab) {
  constexpr int BN = (MODE == 0) ? 192 : 128;
  constexpr int NTW = BN / 32;            // B frags per wave: 6 / 4
  constexpr int TILE = (256 + BN) * 64;   // shorts per ring buffer
  constexpr int NU = 32 + BN / 8;         // staging units: 56 / 48
  constexpr int UPW = NU / 8;             // units per wave: 7 / 6
  __shared__ unsigned short lds[2 * TILE];
  const int nb = blockIdx.x, mb = blockIdx.y;
  const int M0 = mb * 256;
  const int t = threadIdx.x;
  const int w = t >> 6, lane = t & 63, l15 = lane & 15, quad = lane >> 4;
  const int g = lane >> 3, j = lane & 7;
  const int wm = w >> 1, wn = w & 1;

  const unsigned short* Abase = A + (size_t)M0 * DMODEL;
  const unsigned short* Bbase = B + (size_t)nb * BN * DMODEL;

  f32x4 acc[4][NTW] = {};

  auto stage = [&](int buf, int k0, int i0, int i1) {
#pragma unroll
    for (int i = i0; i < i1; ++i) {
      const int u = w * UPW + i;
      if (u < 32) {
        g2l16(Abase + (size_t)(u * 8 + g) * DMODEL + k0 + ((j ^ g) << 3),
              &lds[buf * TILE + u * 512]);
      } else {
        g2l16(Bbase + (size_t)((u - 32) * 8 + g) * DMODEL + k0 + ((j ^ g) << 3),
              &lds[buf * TILE + 16384 + (u - 32) * 512]);
      }
    }
  };

  auto comp = [&](int buf, int kc) {
    const int c = kc * 4 + quad;
    const unsigned short* As_ = &lds[buf * TILE];
    const unsigned short* Bs_ = &lds[buf * TILE + 16384];
    bf16x8 af[4], bv[NTW];
#pragma unroll
    for (int mt = 0; mt < 4; ++mt) {
      const int m = wm * 64 + mt * 16 + l15;
      af[mt] = *(const bf16x8*)&As_[m * 64 + ((c ^ (m & 7)) << 3)];
    }
#pragma unroll
    for (int nt = 0; nt < NTW; ++nt) {
      const int n = wn * (BN / 2) + nt * 16 + l15;
      bv[nt] = *(const bf16x8*)&Bs_[n * 64 + ((c ^ (n & 7)) << 3)];
    }
#pragma unroll
    for (int nt = 0; nt < NTW; ++nt)
#pragma unroll
      for (int mt = 0; mt < 4; ++mt)
        acc[mt][nt] = mfma16(af[mt], bv[nt], acc[mt][nt]);
  };

  stage(0, 0, 0, UPW);
  asm volatile("s_waitcnt vmcnt(0)\n\ts_barrier" ::: "memory");

  int buf = 0;
  for (int tt = 0; tt < 32; ++tt) {
    const bool ps = (tt < 31);
    if (ps) stage(buf ^ 1, tt * 64 + 64, 0, UPW / 2);
    comp(buf, 0);
    if (ps) stage(buf ^ 1, tt * 64 + 64, UPW / 2, UPW);
    comp(buf, 1);
    if (ps) {
      asm volatile("s_waitcnt vmcnt(0)\n\ts_barrier" ::: "memory");
      buf ^= 1;
    }
  }

  // Epilogue. C/D layout: col = l15 (N side), row = quad*4 + reg (M side).
  if (MODE == 0) {
    const size_t NX = (size_t)2 * SEQ * DMODEL;
#pragma unroll
    for (int pp = 0; pp < NTW / 2; ++pp) {
      const int colb = nb * BN + wn * (BN / 2) + pp * 32;  // 32-aligned
      const int z = colb >> 11;          // 0:Q 1:K 2:V
      const int zc = colb & 2047;
      const int h = zc >> 7;             // head
      const int e0 = zc & 127;           // in-head col base (0/32/64/96)
      if (z < 2) {
        const float qscale = (z == 0) ? 0.1275174356f : 1.0f;
        unsigned short* O = obf + (size_t)z * NX;
        const int rt = (e0 >> 5) * 16 + l15;  // rope dim q*16 + r
#pragma unroll
        for (int mt = 0; mt < 4; ++mt)
#pragma unroll
          for (int reg = 0; reg < 4; ++reg) {
            const int m = M0 + wm * 64 + mt * 16 + quad * 4 + reg;
            const int bb = m >> 11, s = m & 2047;
            unsigned short* ob = O + ((size_t)(bb * NH + h) * SEQ + s) * HD;
            const float2 cs = rtab[s * 64 + rt];
            const float x1 = acc[mt][2 * pp][reg], x2 = acc[mt][2 * pp + 1][reg];
            ob[e0 + l15] = f2bf((x1 * cs.x - x2 * cs.y) * qscale);
            ob[e0 + 16 + l15] = f2bf((x2 * cs.x + x1 * cs.y) * qscale);
          }
      } else {
        // V stored transposed (B,H,hd,S) with seq index sigma-permuted within
        // each 64-block: spos = (k>>5)*32 + ((k&15)>>2)*8 + (k&3)*2 + ((k>>4)&1)
        // so attn's packed-P PV reads a consistent k-order (see attn_kernel).
        unsigned short* Vb0 = obf + 2 * NX + (size_t)h * HD * SEQ;
#pragma unroll
        for (int q2 = 0; q2 < 2; ++q2) {
          const int d = e0 + q2 * 16 + l15;
#pragma unroll
          for (int mt = 0; mt < 4; ++mt)
#pragma unroll
            for (int reg = 0; reg < 4; ++reg) {
              const int m = M0 + wm * 64 + mt * 16 + quad * 4 + reg;
              const int bb = m >> 11, s = m & 2047;
              const int spos = (s & ~63) |
                               ((mt >> 1) * 32 + quad * 8 + reg * 2 + (mt & 1));
              unsigned short* ob = Vb0 + (size_t)bb * NH * HD * SEQ;
              ob[(size_t)d * SEQ + spos] = f2bf(acc[mt][2 * pp + q2][reg]);
            }
        }
      }
    }
  } else {
#pragma unroll
    for (int mt = 0; mt < 4; ++mt)
#pragma unroll
      for (int reg = 0; reg < 4; ++reg) {
        const int m = M0 + wm * 64 + mt * 16 + quad * 4 + reg;
#pragma unroll
        for (int nt = 0; nt < NTW; ++nt)
          of32[(size_t)m * DMODEL + nb * BN + wn * (BN / 2) + nt * 16 + l15] =
              acc[mt][nt][reg];
      }
  }
}

// ---------------------------------------------------------------------------
// Flash attention, causal. QBLK=128 (8 waves x 16 rows), KVBLK=64, dbuf K/V.
// Block = one (b,h) x q-tile PAIR (pr, 15-pr), processed sequentially:
// (2pr+2) + (2(15-pr)+2) = 36 kt-iterations for EVERY block -> uniform load,
// immune to dispatch order. Grid 256 = 1 block/CU; bh = gid&31 keeps each
// bh's K/V on one XCD's L2.
// Per iter: stage(kt+1) ; QK^T ; softmax ; P packed via cvt_pk -> b32 LDS
// (skewed, ~2-way); PV reads P as b128 and V in sigma-permuted k-order;
// vmcnt(0)+barrier (loads issued a full iteration earlier -> latency hidden).
// ---------------------------------------------------------------------------
__global__ __launch_bounds__(512, 4) void attn_kernel(const unsigned short* __restrict__ Q,
                                                      const unsigned short* __restrict__ K,
                                                      const unsigned short* __restrict__ Vt,
                                                      unsigned short* __restrict__ Oa) {
  __shared__ unsigned short Ks[2][64 * 128];  // 2 x 16 KB
  __shared__ unsigned short Vs[2][128 * 64];  // 2 x 16 KB
  __shared__ unsigned short Ps[8][1024];      // 8 x 2 KB wave-private P
  const int gid = blockIdx.x;
  const int bh = gid & 31;   // all 8 pair-blocks of one bh on XCD bh%8
  const int pr = gid >> 5;   // pair index 0..7
  const unsigned short* Qb = Q + (size_t)bh * SEQ * HD;
  const unsigned short* Kb = K + (size_t)bh * SEQ * HD;
  const unsigned short* Vb = Vt + (size_t)bh * HD * SEQ;
  const int t = threadIdx.x;
  const int w = t >> 6, lane = t & 63, l15 = lane & 15, quad = lane >> 4;
  const int b = bh >> 4, h = bh & 15;

  // stage K/V tile kt into buffer sb: 512 threads x 2 instr x 16B per tensor.
  auto stage = [&](int sb, int kt) {
    const unsigned short* Kt = Kb + (size_t)(kt * 64) * HD;
    const unsigned short* Vtk = Vb + kt * 64;
#pragma unroll
    for (int i = 0; i < 2; ++i) {
      const int u = i * 512 + t;
      const int key = u >> 4, cs = u & 15;
      g2l16(Kt + (size_t)key * HD + ((cs ^ (key & 7)) << 3),
            &Ks[sb][(i * 512 + w * 64) * 8]);
    }
#pragma unroll
    for (int i = 0; i < 2; ++i) {
      const int u = i * 512 + t;
      const int d = u >> 3, cs = u & 7;
      g2l16(Vtk + (size_t)d * SEQ + ((cs ^ (d & 7)) << 3),
            &Vs[sb][(i * 512 + w * 64) * 8]);
    }
  };

  for (int half = 0; half < 2; ++half) {
    const int qt = half ? 15 - pr : pr;  // q-tile of 128 rows

    // Q fragments: A-layout row = l15, k(hd) = ch*32 + quad*8
    bf16x8 qf[4];
#pragma unroll
    for (int ch = 0; ch < 4; ++ch)
      qf[ch] = *(const bf16x8*)(Qb + (size_t)(qt * 128 + w * 16 + l15) * HD +
                                ch * 32 + quad * 8);

    f32x4 o[8] = {};
    float mrow[4], lrow[4];
#pragma unroll
    for (int reg = 0; reg < 4; ++reg) { mrow[reg] = -1e30f; lrow[reg] = 0.f; }

    const int ktmax = 2 * qt + 1;
    stage(0, 0);
    asm volatile("s_waitcnt vmcnt(0)\n\ts_barrier" ::: "memory");
    int buf = 0;

    for (int kt = 0; kt <= ktmax; ++kt) {
      if (kt < ktmax) stage(buf ^ 1, kt + 1);  // prefetch next tile

      // wave-uniform valid key-tile bound for this iter (rows w*16..w*16+15)
      const int ntm_raw = (qt * 128 + w * 16 + 15 - kt * 64) >> 4;
      const int ntm = ntm_raw > 3 ? 3 : ntm_raw;
      if (ntm >= 0) {
        // S = Q K^T (Q pre-scaled by log2e/sqrt(hd))
        f32x4 s[4] = {};
        __builtin_amdgcn_s_setprio(1);
#pragma unroll
        for (int ch = 0; ch < 4; ++ch) {
          const int c = ch * 4 + quad;
#pragma unroll
          for (int nt = 0; nt < 4; ++nt) {
            if (nt <= ntm) {
              const int n = nt * 16 + l15;
              const bf16x8 bv = *(const bf16x8*)&Ks[buf][n * 128 + ((c ^ (n & 7)) << 3)];
              s[nt] = mfma16(qf[ch], bv, s[nt]);
            }
          }
        }
        __builtin_amdgcn_s_setprio(0);

        if (kt >= 2 * qt) {  // diagonal zone: causal mask
#pragma unroll
          for (int nt = 0; nt < 4; ++nt)
#pragma unroll
            for (int reg = 0; reg < 4; ++reg) {
              const int rr = qt * 128 + w * 16 + quad * 4 + reg;
              const int cc = kt * 64 + nt * 16 + l15;
              if (cc > rr) s[nt][reg] = -1e30f;
            }
        }

        // online softmax in log2 domain, defer-max rescale (THR=8)
#pragma unroll
        for (int reg = 0; reg < 4; ++reg) {
          float vmax = fmaxf(fmaxf(s[0][reg], s[1][reg]), fmaxf(s[2][reg], s[3][reg]));
          vmax = red_max16(vmax);
          const float mo = mrow[reg];
          float mn = mo;
          if (!__all(vmax <= mo + 8.0f)) {  // wave-uniform branch
            mn = fmaxf(mo, vmax);
            const float alpha = exp2f(mo - mn);
            mrow[reg] = mn;
            lrow[reg] *= alpha;
#pragma unroll
            for (int nt = 0; nt < 8; ++nt) o[nt][reg] *= alpha;
          }
          float rs = 0.f;
#pragma unroll
          for (int nt = 0; nt < 4; ++nt) {
            const float p_ = exp2f(s[nt][reg] - mn);
            s[nt][reg] = p_;
            rs += p_;
          }
          rs = red_sum16(rs);
          lrow[reg] += rs;
        }

        // P pack: u32 = cvt_pk(s[2np], s[2np+1]) = keys (np*32+l15, np*32+16+l15)
        // for row r=quad*4+reg. Skew: phys np ^= (r>>2)&1; 16B-unit rotated by r.
        unsigned short* Pw = Ps[w];
#pragma unroll
        for (int np = 0; np < 2; ++np)
#pragma unroll
          for (int reg = 0; reg < 4; ++reg) {
            unsigned int u;
            asm("v_cvt_pk_bf16_f32 %0, %1, %2"
                : "=v"(u)
                : "v"(s[np * 2][reg]), "v"(s[np * 2 + 1][reg]));
            const int r = quad * 4 + reg;
            const int ph = ((np ^ (quad & 1)) * 4 + (l15 >> 2) + r) & 7;
            *(unsigned int*)&Pw[r * 64 + ph * 8 + (l15 & 3) * 2] = u;
          }
        asm volatile("" ::: "memory");  // order P writes before P reads

        // O += P V  (V keys sigma-permuted to match packed-P k-order)
        const int ch2max = (ntm >= 2) ? 1 : 0;
        __builtin_amdgcn_s_setprio(1);
#pragma unroll
        for (int ch2 = 0; ch2 < 2; ++ch2) {
          if (ch2 <= ch2max) {
            const int pnp = ch2 ^ ((l15 >> 2) & 1);
            const int ph = (pnp * 4 + quad + l15) & 7;
            const bf16x8 pa = *(const bf16x8*)&Pw[l15 * 64 + ph * 8];
            const int c = ch2 * 4 + quad;
#pragma unroll
            for (int nt = 0; nt < 8; ++nt) {
              const int d = nt * 16 + l15;
              const bf16x8 vv = *(const bf16x8*)&Vs[buf][d * 64 + ((c ^ (d & 7)) << 3)];
              o[nt] = mfma16(pa, vv, o[nt]);
            }
          }
        }
        __builtin_amdgcn_s_setprio(0);
      }

      // single barrier per iter: next tile's loads (issued at top) now land.
      asm volatile("s_waitcnt vmcnt(0)\n\ts_barrier" ::: "memory");
      buf ^= 1;
    }

    // epilogue: normalize and store attn output as (B*S, D) bf16
#pragma unroll
    for (int reg = 0; reg < 4; ++reg) {
      const int sq = qt * 128 + w * 16 + quad * 4 + reg;
      const float inv_l = 1.0f / lrow[reg];
      unsigned short* ob = Oa + (size_t)(b * SEQ + sq) * DMODEL + h * HD;
#pragma unroll
      for (int nt = 0; nt < 8; ++nt) ob[nt * 16 + l15] = f2bf(o[nt][reg] * inv_l);
    }
  }
}

extern "C" void kernel_launch(void* const* d_in, const int* in_sizes, int n_in,
                              void* d_out, int out_size, void* d_ws, size_t ws_size,
                              hipStream_t stream) {
  const float* x = (const float*)d_in[0];
  const float* Wq = (const float*)d_in[1];
  const float* Wk = (const float*)d_in[2];
  const float* Wv = (const float*)d_in[3];
  const float* Wo = (const float*)d_in[4];
  float* out = (float*)d_out;

  const size_t NX = (size_t)2 * SEQ * DMODEL;
  const size_t NW = (size_t)DMODEL * DMODEL;
  unsigned short* ws = (unsigned short*)d_ws;
  unsigned short* xb = ws;
  unsigned short* wqb = xb + NX;   // wq/wk/wv contiguous -> fused N=6144 B operand
  unsigned short* wkb = wqb + NW;
  unsigned short* wvb = wkb + NW;
  unsigned short* wob = wvb + NW;
  unsigned short* qb = wob + NW;  // (B,H,S,hd) permuted-hd, rope'd, *log2e/sqrt(hd)
  unsigned short* kb = qb + NX;   // (B,H,S,hd) permuted-hd, rope'd
  unsigned short* vb = kb + NX;   // (B,H,hd,S), seq sigma-permuted per 64-block
  unsigned short* ab = vb + NX;   // (B*S, D)
  float2* rtab = (float2*)(ab + NX);  // 2048 x 64 cos/sin (1 MB)

  cvt_all<<<25088, 256, 0, stream>>>(x, Wq, Wk, Wv, Wo, ws, rtab);
  gemm_pipe<0><<<dim3(32, 16), 512, 0, stream>>>(xb, wqb, qb, nullptr, rtab);
  attn_kernel<<<256, 512, 0, stream>>>(qb, kb, vb, ab);
  gemm_pipe<1><<<dim3(16, 16), 512, 0, stream>>>(ab, wob, nullptr, out, nullptr);
}

// Round 8
// 357.358 us; speedup vs baseline: 1.0762x; 1.0762x over previous
//
#include <hip/hip_runtime.h>

// MHA forward: x(2,2048,2048) fp32, Wq/Wk/Wv/Wo (2048,2048) fp32 -> out fp32.
// R11: attn = R6 skeleton (QBLK=64, 4-wave blocks, pairs (pr,31-pr) -> 33
//      iters/block uniform, grid 512 = 2 blocks/CU co-resident, 72 KB LDS)
//      + R9 inner loop (cvt_pk packed P via b32 skewed stores, sigma-V PV,
//      diagonal ch2max skip, defer-max, setprio). R10 showed balance at
//      1 block/CU exposes the latency chain (3.1 vs 2.1 us/iter-vol);
//      R6 showed the balanced 2-block structure is VALU-bound (60%) -> this
//      applies the VALU cut exactly where it pays.
//      GEMMs (BN=192 ring-2, sigma-V epilogue) and cvt unchanged.

#define SEQ 2048
#define DMODEL 2048
#define NH 16
#define HD 128

typedef __attribute__((ext_vector_type(8))) short bf16x8;  // 8 bf16 = 4 VGPRs
typedef __attribute__((ext_vector_type(4))) float f32x4;

__device__ __forceinline__ unsigned short f2bf(float f) {  // RNE fp32->bf16
  unsigned int u = __float_as_uint(f);
  u += 0x7fffu + ((u >> 16) & 1u);
  return (unsigned short)(u >> 16);
}

__device__ __forceinline__ void g2l16(const void* g, void* l) {
  __builtin_amdgcn_global_load_lds((const __attribute__((address_space(1))) void*)g,
                                   (__attribute__((address_space(3))) void*)l,
                                   16, 0, 0);
}

__device__ __forceinline__ f32x4 mfma16(bf16x8 a, bf16x8 b, f32x4 c) {
  return __builtin_amdgcn_mfma_f32_16x16x32_bf16(a, b, c, 0, 0, 0);
}

template <int CTRL>
__device__ __forceinline__ float dpp_ror(float v) {
  return __int_as_float(__builtin_amdgcn_mov_dpp(__float_as_int(v), CTRL, 0xf, 0xf, false));
}
__device__ __forceinline__ float red_max16(float v) {
  v = fmaxf(v, dpp_ror<0x128>(v));
  v = fmaxf(v, dpp_ror<0x124>(v));
  v = fmaxf(v, dpp_ror<0x122>(v));
  v = fmaxf(v, dpp_ror<0x121>(v));
  return v;
}
__device__ __forceinline__ float red_sum16(float v) {
  v += dpp_ror<0x128>(v);
  v += dpp_ror<0x124>(v);
  v += dpp_ror<0x122>(v);
  v += dpp_ror<0x121>(v);
  return v;
}

// one launch: converts x + all four weights to bf16, permutes Wq/Wk rows
// within-head (RoPE pairs -> adjacent 16-col fragments), fills rope table.
__global__ __launch_bounds__(256) void cvt_all(const float* __restrict__ x,
                                               const float* __restrict__ wq,
                                               const float* __restrict__ wk,
                                               const float* __restrict__ wv,
                                               const float* __restrict__ wo,
                                               unsigned short* __restrict__ dst0,
                                               float2* __restrict__ rtab) {
  const int b = blockIdx.x;
  if (b >= 24576) {  // rope cos/sin table: 2048 x 64
    const int idx = (b - 24576) * 256 + threadIdx.x;  // [0, 131072)
    const int s = idx >> 6, d = idx & 63;
    float sn, cs;
    sincosf((float)s * exp2f(-0.20762050593046f * (float)d), &sn, &cs);
    rtab[idx] = make_float2(cs, sn);
    return;
  }
  const float* src;
  unsigned short* dst;
  int idx, r = -1;
  if (b < 8192) {  // x: 2097152 float4's
    src = x; dst = dst0; idx = b * 256 + threadIdx.x;
  } else {
    r = (b - 8192) >> 12;  // 4096 blocks per weight
    src = (r == 0) ? wq : (r == 1) ? wk : (r == 2) ? wv : wo;
    dst = dst0 + (size_t)2 * SEQ * DMODEL + (size_t)r * DMODEL * DMODEL;
    idx = ((b - 8192) & 4095) * 256 + threadIdx.x;
  }
  const float4 v = ((const float4*)src)[idx];
  ushort4 o;
  o.x = f2bf(v.x); o.y = f2bf(v.y); o.z = f2bf(v.z); o.w = f2bf(v.w);
  int widx = idx;
  if (r == 0 || r == 1) {  // permute Wq/Wk output-feature rows within head
    const int row = idx >> 9, col = idx & 511;
    const int o_ = row & 127;
    const int e = (((o_ >> 4) & 3) << 5) | (((o_ >> 6) & 1) << 4) | (o_ & 15);
    widx = (((row & ~127) | e) << 9) | col;
  }
  ((ushort4*)dst)[widx] = o;
}

// ---------------------------------------------------------------------------
// Pipelined GEMM core: C[m,n] = sum_k A[m,k]*B[n,k].
// BM=256, BN=192(MODE0)/128(MODE1), BK=64. 512 threads = 8 waves (4M x 2N).
// Ring-2 LDS; stage t+1 interleaved with compute of t; vmcnt(0)+barrier per
// tile. Natural dim3 grid (gridDim.x%8==0 -> B panels XCD-L2-resident).
// MODE 0: fused QKV; V keys are stored sigma-permuted within 64-blocks so the
// attention kernel's packed-P PV MFMA sees a consistent k-order.
// ---------------------------------------------------------------------------
template <int MODE>
__global__ __launch_bounds__(512, 2) void gemm_pipe(
    const unsigned short* __restrict__ A,
    const unsigned short* __restrict__ B,
    unsigned short* __restrict__ obf,   // MODE0: qb (kb=+NX, vb=+2NX)
    float* __restrict__ of32,           // MODE1: output
    const float2* __restrict__ rtab) {
  constexpr int BN = (MODE == 0) ? 192 : 128;
  constexpr int NTW = BN / 32;            // B frags per wave: 6 / 4
  constexpr int TILE = (256 + BN) * 64;   // shorts per ring buffer
  constexpr int NU = 32 + BN / 8;         // staging units: 56 / 48
  constexpr int UPW = NU / 8;             // units per wave: 7 / 6
  __shared__ unsigned short lds[2 * TILE];
  const int nb = blockIdx.x, mb = blockIdx.y;
  const int M0 = mb * 256;
  const int t = threadIdx.x;
  const int w = t >> 6, lane = t & 63, l15 = lane & 15, quad = lane >> 4;
  const int g = lane >> 3, j = lane & 7;
  const int wm = w >> 1, wn = w & 1;

  const unsigned short* Abase = A + (size_t)M0 * DMODEL;
  const unsigned short* Bbase = B + (size_t)nb * BN * DMODEL;

  f32x4 acc[4][NTW] = {};

  auto stage = [&](int buf, int k0, int i0, int i1) {
#pragma unroll
    for (int i = i0; i < i1; ++i) {
      const int u = w * UPW + i;
      if (u < 32) {
        g2l16(Abase + (size_t)(u * 8 + g) * DMODEL + k0 + ((j ^ g) << 3),
              &lds[buf * TILE + u * 512]);
      } else {
        g2l16(Bbase + (size_t)((u - 32) * 8 + g) * DMODEL + k0 + ((j ^ g) << 3),
              &lds[buf * TILE + 16384 + (u - 32) * 512]);
      }
    }
  };

  auto comp = [&](int buf, int kc) {
    const int c = kc * 4 + quad;
    const unsigned short* As_ = &lds[buf * TILE];
    const unsigned short* Bs_ = &lds[buf * TILE + 16384];
    bf16x8 af[4], bv[NTW];
#pragma unroll
    for (int mt = 0; mt < 4; ++mt) {
      const int m = wm * 64 + mt * 16 + l15;
      af[mt] = *(const bf16x8*)&As_[m * 64 + ((c ^ (m & 7)) << 3)];
    }
#pragma unroll
    for (int nt = 0; nt < NTW; ++nt) {
      const int n = wn * (BN / 2) + nt * 16 + l15;
      bv[nt] = *(const bf16x8*)&Bs_[n * 64 + ((c ^ (n & 7)) << 3)];
    }
#pragma unroll
    for (int nt = 0; nt < NTW; ++nt)
#pragma unroll
      for (int mt = 0; mt < 4; ++mt)
        acc[mt][nt] = mfma16(af[mt], bv[nt], acc[mt][nt]);
  };

  stage(0, 0, 0, UPW);
  asm volatile("s_waitcnt vmcnt(0)\n\ts_barrier" ::: "memory");

  int buf = 0;
  for (int tt = 0; tt < 32; ++tt) {
    const bool ps = (tt < 31);
    if (ps) stage(buf ^ 1, tt * 64 + 64, 0, UPW / 2);
    comp(buf, 0);
    if (ps) stage(buf ^ 1, tt * 64 + 64, UPW / 2, UPW);
    comp(buf, 1);
    if (ps) {
      asm volatile("s_waitcnt vmcnt(0)\n\ts_barrier" ::: "memory");
      buf ^= 1;
    }
  }

  // Epilogue. C/D layout: col = l15 (N side), row = quad*4 + reg (M side).
  if (MODE == 0) {
    const size_t NX = (size_t)2 * SEQ * DMODEL;
#pragma unroll
    for (int pp = 0; pp < NTW / 2; ++pp) {
      const int colb = nb * BN + wn * (BN / 2) + pp * 32;  // 32-aligned
      const int z = colb >> 11;          // 0:Q 1:K 2:V
      const int zc = colb & 2047;
      const int h = zc >> 7;             // head
      const int e0 = zc & 127;           // in-head col base (0/32/64/96)
      if (z < 2) {
        const float qscale = (z == 0) ? 0.1275174356f : 1.0f;
        unsigned short* O = obf + (size_t)z * NX;
        const int rt = (e0 >> 5) * 16 + l15;  // rope dim q*16 + r
#pragma unroll
        for (int mt = 0; mt < 4; ++mt)
#pragma unroll
          for (int reg = 0; reg < 4; ++reg) {
            const int m = M0 + wm * 64 + mt * 16 + quad * 4 + reg;
            const int bb = m >> 11, s = m & 2047;
            unsigned short* ob = O + ((size_t)(bb * NH + h) * SEQ + s) * HD;
            const float2 cs = rtab[s * 64 + rt];
            const float x1 = acc[mt][2 * pp][reg], x2 = acc[mt][2 * pp + 1][reg];
            ob[e0 + l15] = f2bf((x1 * cs.x - x2 * cs.y) * qscale);
            ob[e0 + 16 + l15] = f2bf((x2 * cs.x + x1 * cs.y) * qscale);
          }
      } else {
        // V stored transposed (B,H,hd,S) with seq index sigma-permuted within
        // each 64-block: spos = (k>>5)*32 + ((k&15)>>2)*8 + (k&3)*2 + ((k>>4)&1)
        // so attn's packed-P PV reads a consistent k-order (see attn_kernel).
        unsigned short* Vb0 = obf + 2 * NX + (size_t)h * HD * SEQ;
#pragma unroll
        for (int q2 = 0; q2 < 2; ++q2) {
          const int d = e0 + q2 * 16 + l15;
#pragma unroll
          for (int mt = 0; mt < 4; ++mt)
#pragma unroll
            for (int reg = 0; reg < 4; ++reg) {
              const int m = M0 + wm * 64 + mt * 16 + quad * 4 + reg;
              const int bb = m >> 11, s = m & 2047;
              const int spos = (s & ~63) |
                               ((mt >> 1) * 32 + quad * 8 + reg * 2 + (mt & 1));
              unsigned short* ob = Vb0 + (size_t)bb * NH * HD * SEQ;
              ob[(size_t)d * SEQ + spos] = f2bf(acc[mt][2 * pp + q2][reg]);
            }
        }
      }
    }
  } else {
#pragma unroll
    for (int mt = 0; mt < 4; ++mt)
#pragma unroll
      for (int reg = 0; reg < 4; ++reg) {
        const int m = M0 + wm * 64 + mt * 16 + quad * 4 + reg;
#pragma unroll
        for (int nt = 0; nt < NTW; ++nt)
          of32[(size_t)m * DMODEL + nb * BN + wn * (BN / 2) + nt * 16 + l15] =
              acc[mt][nt][reg];
      }
  }
}

// ---------------------------------------------------------------------------
// Flash attention, causal. QBLK=64 (4 waves x 16 rows), KVBLK=64, dbuf K/V.
// Block = one (b,h) x q-tile PAIR (pr, 31-pr): (pr+1)+(32-pr) = 33 kt-iters
// for EVERY block -> uniform load. Grid 512 = 2 blocks/CU (72 KB LDS) so
// co-resident blocks overlap each other's barrier/latency stalls.
// Per iter: stage(kt+1) ; QK^T ; softmax ; P packed via cvt_pk -> b32 LDS
// (skewed, ~2-way); PV reads P as b128 and V in sigma-permuted k-order;
// vmcnt(0)+barrier (loads issued a full iteration earlier -> latency hidden).
// ---------------------------------------------------------------------------
__global__ __launch_bounds__(256) void attn_kernel(const unsigned short* __restrict__ Q,
                                                   const unsigned short* __restrict__ K,
                                                   const unsigned short* __restrict__ Vt,
                                                   unsigned short* __restrict__ Oa) {
  __shared__ unsigned short Ks[2][64 * 128];  // 2 x 16 KB
  __shared__ unsigned short Vs[2][128 * 64];  // 2 x 16 KB
  __shared__ unsigned short Ps[4][1024];      // 4 x 2 KB wave-private P
  const int gid = blockIdx.x;
  const int bh = gid & 31;   // all 16 pair-blocks of one bh on XCD bh%8
  const int pr = gid >> 5;   // pair index 0..15
  const unsigned short* Qb = Q + (size_t)bh * SEQ * HD;
  const unsigned short* Kb = K + (size_t)bh * SEQ * HD;
  const unsigned short* Vb = Vt + (size_t)bh * HD * SEQ;
  const int t = threadIdx.x;
  const int w = t >> 6, lane = t & 63, l15 = lane & 15, quad = lane >> 4;
  const int b = bh >> 4, h = bh & 15;
  const int uA = w * 64 + lane;  // staging unit base (i*256 added per instr)

  // stage K/V tile kt into buffer sb: 256 threads x 4 instr x 16B per tensor.
  auto stage = [&](int sb, int kt) {
    const unsigned short* Kt = Kb + (size_t)(kt * 64) * HD;
    const unsigned short* Vtk = Vb + kt * 64;
#pragma unroll
    for (int i = 0; i < 4; ++i) {
      const int u = i * 256 + uA;
      const int key = u >> 4, cs = u & 15;
      g2l16(Kt + (size_t)key * HD + ((cs ^ (key & 7)) << 3),
            &Ks[sb][(i * 256 + w * 64) * 8]);
    }
#pragma unroll
    for (int i = 0; i < 4; ++i) {
      const int u = i * 256 + uA;
      const int d = u >> 3, cs = u & 7;
      g2l16(Vtk + (size_t)d * SEQ + ((cs ^ (d & 7)) << 3),
            &Vs[sb][(i * 256 + w * 64) * 8]);
    }
  };

  for (int half = 0; half < 2; ++half) {
    const int qt = half ? 31 - pr : pr;  // q-tile of 64 rows; kt = 0..qt

    // Q fragments: A-layout row = l15, k(hd) = ch*32 + quad*8
    bf16x8 qf[4];
#pragma unroll
    for (int ch = 0; ch < 4; ++ch)
      qf[ch] = *(const bf16x8*)(Qb + (size_t)(qt * 64 + w * 16 + l15) * HD +
                                ch * 32 + quad * 8);

    f32x4 o[8] = {};
    float mrow[4], lrow[4];
#pragma unroll
    for (int reg = 0; reg < 4; ++reg) { mrow[reg] = -1e30f; lrow[reg] = 0.f; }

    stage(0, 0);
    asm volatile("s_waitcnt vmcnt(0)\n\ts_barrier" ::: "memory");
    int buf = 0;

    for (int kt = 0; kt <= qt; ++kt) {
      if (kt < qt) stage(buf ^ 1, kt + 1);  // prefetch next tile

      // Diagonal tile: wave w only needs key tiles nt <= w (rest masked).
      const bool diag = (kt == qt);
      const int ntm = diag ? w : 3;

      // S = Q K^T (Q pre-scaled by log2e/sqrt(hd))
      f32x4 s[4] = {};
      __builtin_amdgcn_s_setprio(1);
#pragma unroll
      for (int ch = 0; ch < 4; ++ch) {
        const int c = ch * 4 + quad;
#pragma unroll
        for (int nt = 0; nt < 4; ++nt) {
          if (nt <= ntm) {
            const int n = nt * 16 + l15;
            const bf16x8 bv = *(const bf16x8*)&Ks[buf][n * 128 + ((c ^ (n & 7)) << 3)];
            s[nt] = mfma16(qf[ch], bv, s[nt]);
          }
        }
      }
      __builtin_amdgcn_s_setprio(0);

      if (diag) {  // causal mask within 64x64 diagonal tile
#pragma unroll
        for (int nt = 0; nt < 4; ++nt)
#pragma unroll
          for (int reg = 0; reg < 4; ++reg) {
            const int rr = w * 16 + quad * 4 + reg;
            const int cc = nt * 16 + l15;
            if (cc > rr) s[nt][reg] = -1e30f;
          }
      }

      // online softmax in log2 domain, defer-max rescale (THR=8)
#pragma unroll
      for (int reg = 0; reg < 4; ++reg) {
        float vmax = fmaxf(fmaxf(s[0][reg], s[1][reg]), fmaxf(s[2][reg], s[3][reg]));
        vmax = red_max16(vmax);
        const float mo = mrow[reg];
        float mn = mo;
        if (!__all(vmax <= mo + 8.0f)) {  // wave-uniform branch
          mn = fmaxf(mo, vmax);
          const float alpha = exp2f(mo - mn);
          mrow[reg] = mn;
          lrow[reg] *= alpha;
#pragma unroll
          for (int nt = 0; nt < 8; ++nt) o[nt][reg] *= alpha;
        }
        float rs = 0.f;
#pragma unroll
        for (int nt = 0; nt < 4; ++nt) {
          const float p_ = exp2f(s[nt][reg] - mn);
          s[nt][reg] = p_;
          rs += p_;
        }
        rs = red_sum16(rs);
        lrow[reg] += rs;
      }

      // P pack: u32 = cvt_pk(s[2np], s[2np+1]) = keys (np*32+l15, np*32+16+l15)
      // for row r=quad*4+reg. Skew: phys np ^= (r>>2)&1; 16B-unit rotated by r.
      unsigned short* Pw = Ps[w];
#pragma unroll
      for (int np = 0; np < 2; ++np)
#pragma unroll
        for (int reg = 0; reg < 4; ++reg) {
          unsigned int u;
          asm("v_cvt_pk_bf16_f32 %0, %1, %2"
              : "=v"(u)
              : "v"(s[np * 2][reg]), "v"(s[np * 2 + 1][reg]));
          const int r = quad * 4 + reg;
          const int ph = ((np ^ (quad & 1)) * 4 + (l15 >> 2) + r) & 7;
          *(unsigned int*)&Pw[r * 64 + ph * 8 + (l15 & 3) * 2] = u;
        }
      asm volatile("" ::: "memory");  // order P writes before P reads

      // O += P V  (V keys sigma-permuted to match packed-P k-order)
      const int ch2max = (ntm >= 2) ? 1 : 0;
      __builtin_amdgcn_s_setprio(1);
#pragma unroll
      for (int ch2 = 0; ch2 < 2; ++ch2) {
        if (ch2 <= ch2max) {
          const int pnp = ch2 ^ ((l15 >> 2) & 1);
          const int ph = (pnp * 4 + quad + l15) & 7;
          const bf16x8 pa = *(const bf16x8*)&Pw[l15 * 64 + ph * 8];
          const int c = ch2 * 4 + quad;
#pragma unroll
          for (int nt = 0; nt < 8; ++nt) {
            const int d = nt * 16 + l15;
            const bf16x8 vv = *(const bf16x8*)&Vs[buf][d * 64 + ((c ^ (d & 7)) << 3)];
            o[nt] = mfma16(pa, vv, o[nt]);
          }
        }
      }
      __builtin_amdgcn_s_setprio(0);

      // single barrier per iter: next tile's loads (issued at top) now land.
      asm volatile("s_waitcnt vmcnt(0)\n\ts_barrier" ::: "memory");
      buf ^= 1;
    }

    // epilogue: normalize and store attn output as (B*S, D) bf16
#pragma unroll
    for (int reg = 0; reg < 4; ++reg) {
      const int sq = qt * 64 + w * 16 + quad * 4 + reg;
      const float inv_l = 1.0f / lrow[reg];
      unsigned short* ob = Oa + (size_t)(b * SEQ + sq) * DMODEL + h * HD;
#pragma unroll
      for (int nt = 0; nt < 8; ++nt) ob[nt * 16 + l15] = f2bf(o[nt][reg] * inv_l);
    }
  }
}

extern "C" void kernel_launch(void* const* d_in, const int* in_sizes, int n_in,
                              void* d_out, int out_size, void* d_ws, size_t ws_size,
                              hipStream_t stream) {
  const float* x = (const float*)d_in[0];
  const float* Wq = (const float*)d_in[1];
  const float* Wk = (const float*)d_in[2];
  const float* Wv = (const float*)d_in[3];
  const float* Wo = (const float*)d_in[4];
  float* out = (float*)d_out;

  const size_t NX = (size_t)2 * SEQ * DMODEL;
  const size_t NW = (size_t)DMODEL * DMODEL;
  unsigned short* ws = (unsigned short*)d_ws;
  unsigned short* xb = ws;
  unsigned short* wqb = xb + NX;   // wq/wk/wv contiguous -> fused N=6144 B operand
  unsigned short* wkb = wqb + NW;
  unsigned short* wvb = wkb + NW;
  unsigned short* wob = wvb + NW;
  unsigned short* qb = wob + NW;  // (B,H,S,hd) permuted-hd, rope'd, *log2e/sqrt(hd)
  unsigned short* kb = qb + NX;   // (B,H,S,hd) permuted-hd, rope'd
  unsigned short* vb = kb + NX;   // (B,H,hd,S), seq sigma-permuted per 64-block
  unsigned short* ab = vb + NX;   // (B*S, D)
  float2* rtab = (float2*)(ab + NX);  // 2048 x 64 cos/sin (1 MB)

  cvt_all<<<25088, 256, 0, stream>>>(x, Wq, Wk, Wv, Wo, ws, rtab);
  gemm_pipe<0><<<dim3(32, 16), 512, 0, stream>>>(xb, wqb, qb, nullptr, rtab);
  attn_kernel<<<512, 256, 0, stream>>>(qb, kb, vb, ab);
  gemm_pipe<1><<<dim3(16, 16), 512, 0, stream>>>(ab, wob, nullptr, out, nullptr);
}